// Round 8
// baseline (363.126 us; speedup 1.0000x reference)
//
#include <hip/hip_runtime.h>
#include <hip/hip_bf16.h>
#include <math.h>

// GQA attention forward, MI355X. Round 16: single fused kernel, SOFTWARE grid
// barrier (plain launch — r14's cooperative launch failed under graph capture).
// Stage bodies verbatim from r13 (verified 165.4us / absmax 0.0078).
// 512 blocks x 256 thr, 46.6KB LDS union -> 3 blocks/CU capacity >= 2 needed,
// all blocks co-resident (persistent-grid). Barrier: device-scope atomics in
// d_ws at +32MB, zeroed by hipMemsetAsync in kernel_launch (graph-capturable).
//  0: prep  (1416 vblocks, grid-stride)
//  1: proj  (768 vblocks, grid-stride)
//  2: attn  (512 vblocks exact; qt-pairing balance preserved)
//  3: oproj (512 vblocks exact)
// ws (u16): Xq 2M | Xk 2M | Xv 2M | Wt 1.5M | wot 1M | Qr 2M | Kr 512K | Vrt 512K | AO 2M | rope 512KB(f32) | ... | bar @32MB

#define SEQ 2048
#define DM 1024
#define HD 64

using u16 = unsigned short;
typedef __attribute__((ext_vector_type(8))) short bf16x8;
typedef __attribute__((ext_vector_type(4))) float f32x4;

// 1/sqrt(64) * log2(e): softmax in exp2 domain.
#define QSCALE 0.18033688011112042f

__device__ __forceinline__ u16 f2b(float f) {              // RNE
    union { float f; unsigned int i; } v; v.f = f;
    unsigned int u = v.i;
    return (u16)((u + 0x7fffu + ((u >> 16) & 1u)) >> 16);
}
__device__ __forceinline__ u16 f2b_fast(float f) {         // biased round
    union { float f; unsigned int i; } v; v.f = f;
    return (u16)((v.i + 0x8000u) >> 16);
}

// Software grid barrier: bar[id] = arrival counter, bar[id+8] = release flag.
// All state zeroed before launch. Device-scope atomics (default on global).
__device__ __forceinline__ void gbar(unsigned int* bar, int id, int nb) {
    __syncthreads();
    if (threadIdx.x == 0) {
        __threadfence();                                   // release my writes
        unsigned int a = atomicAdd(&bar[id], 1u);
        if (a == (unsigned int)(nb - 1)) {
            atomicExch(&bar[id + 8], 1u);                  // open the gate
        } else {
            while (atomicAdd(&bar[id + 8], 0u) == 0u)      // coherent RMW read
                __builtin_amdgcn_s_sleep(2);
        }
        __threadfence();                                   // acquire
    }
    __syncthreads();
}

__global__ __launch_bounds__(256) void gqa_fused(
    const float* __restrict__ qin, const float* __restrict__ kin, const float* __restrict__ vin,
    const float* __restrict__ Wq, const float* __restrict__ Wk,
    const float* __restrict__ Wv, const float* __restrict__ Wo,
    const float* __restrict__ bq, const float* __restrict__ bk,
    const float* __restrict__ bv, const float* __restrict__ bo,
    float* __restrict__ out,
    u16* __restrict__ Xq, u16* __restrict__ Xk, u16* __restrict__ Xv,
    u16* __restrict__ Wt, u16* __restrict__ wot,
    u16* __restrict__ Qr, u16* __restrict__ Kr, u16* __restrict__ Vrt,
    u16* __restrict__ AO, float2* __restrict__ rope, unsigned int* __restrict__ bar)
{
    __shared__ __align__(16) char SMEM[46592];
    const int t = threadIdx.x;
    const int NB = gridDim.x;

    // ================================================== stage 0: prep
    {
        short (*T)[72] = reinterpret_cast<short (*)[72]>(SMEM);   // [64][72]
        for (int b = blockIdx.x; b < 1416; b += NB) {
            if (b < 640) {
                const float* W; u16* dst; int N, t0, rowoff;
                if (b < 256)      { W = Wq; dst = Wt;  N = 1024; t0 = b;       rowoff = 0; }
                else if (b < 320) { W = Wk; dst = Wt;  N = 256;  t0 = b - 256; rowoff = 1024; }
                else if (b < 384) { W = Wv; dst = Wt;  N = 256;  t0 = b - 320; rowoff = 1280; }
                else              { W = Wo; dst = wot; N = 1024; t0 = b - 384; rowoff = 0; }
                const int ntn = N >> 6;
                const int k0 = (t0 / ntn) * 64, n0 = (t0 % ntn) * 64;
                const int r = t >> 4, c4 = (t & 15) * 4;
                #pragma unroll
                for (int rr = 0; rr < 4; ++rr) {
                    const int k = r + rr * 16;
                    float4 w4 = *reinterpret_cast<const float4*>(W + (size_t)(k0 + k) * N + n0 + c4);
                    T[c4 + 0][k] = (short)f2b(w4.x);
                    T[c4 + 1][k] = (short)f2b(w4.y);
                    T[c4 + 2][k] = (short)f2b(w4.z);
                    T[c4 + 3][k] = (short)f2b(w4.w);
                }
                __syncthreads();
                const int n = t >> 2, ck = (t & 3) * 16;
                if (b < 384) {
                    const int nt = (rowoff + n0) >> 6, kt = k0 >> 6;
                    char* dp = (char*)(dst + (size_t)(nt * 16 + kt) * 4096) + n * 128;
                    const int g0 = (t & 3) * 2, rx = n & 7;
                    *reinterpret_cast<bf16x8*>(dp + (((g0    ) ^ rx) << 4)) =
                        *reinterpret_cast<const bf16x8*>(&T[n][ck]);
                    *reinterpret_cast<bf16x8*>(dp + (((g0 + 1) ^ rx) << 4)) =
                        *reinterpret_cast<const bf16x8*>(&T[n][ck + 8]);
                } else {
                    u16* dp = dst + (size_t)(n0 + n) * DM + k0 + ck;
                    *reinterpret_cast<bf16x8*>(dp)     = *reinterpret_cast<const bf16x8*>(&T[n][ck]);
                    *reinterpret_cast<bf16x8*>(dp + 8) = *reinterpret_cast<const bf16x8*>(&T[n][ck + 8]);
                }
            } else if (b < 1408) {
                const int idx = b - 640;
                const int which = idx >> 8;
                const int ib = idx & 255;
                const float* src = (which == 0) ? qin : (which == 1) ? kin : vin;
                u16* dst = (which == 0) ? Xq : (which == 1) ? Xk : Xv;
                const int m  = ib * 8 + (t >> 5);          // global row
                const int mt = m >> 6, r = m & 63, rx = r & 7;
                const int col0 = (t & 31) * 32;
                const float* sp = src + (size_t)m * 1024 + col0;
                #pragma unroll
                for (int c = 0; c < 4; ++c) {
                    float4 x0 = *reinterpret_cast<const float4*>(sp + c * 8);
                    float4 x1 = *reinterpret_cast<const float4*>(sp + c * 8 + 4);
                    bf16x8 o;
                    o[0] = (short)f2b(x0.x); o[1] = (short)f2b(x0.y);
                    o[2] = (short)f2b(x0.z); o[3] = (short)f2b(x0.w);
                    o[4] = (short)f2b(x1.x); o[5] = (short)f2b(x1.y);
                    o[6] = (short)f2b(x1.z); o[7] = (short)f2b(x1.w);
                    const int col = col0 + c * 8;
                    const int kt = col >> 6, g = (col & 63) >> 3;
                    char* dp = (char*)(dst + (size_t)(mt * 16 + kt) * 4096)
                             + r * 128 + ((g ^ rx) << 4);
                    *reinterpret_cast<bf16x8*>(dp) = o;
                }
            } else {
                const int m = (b - 1408) * 256 + t;
                float2* rp = rope + (size_t)m * 32;
                for (int pi = 0; pi < 32; ++pi) {
                    const float theta = exp2f(-0.8304820237f * (float)pi);  // 10000^(-pi/16)
                    float sn, cs;
                    sincosf((float)m * theta, &sn, &cs);
                    rp[pi] = make_float2(cs, sn);
                }
            }
            __syncthreads();
        }
    }
    gbar(bar, 0, NB);

    // ================================================== stage 1: proj
    {
        u16 (*As)[4096] = reinterpret_cast<u16 (*)[4096]>(SMEM);           // [2][4096]
        u16 (*Bs)[4096] = reinterpret_cast<u16 (*)[4096]>(SMEM + 16384);   // [2][4096]
        const int w = t >> 6, lane = t & 63, lm = lane & 15, quad = lane >> 4;

        for (int vb = blockIdx.x; vb < 768; vb += NB) {
            const int n0 = (vb % 24) * 64, m0 = (vb / 24) * 64;
            const int zone = (n0 < 1024) ? 0 : (n0 < 1280) ? 1 : 2;
            const u16* __restrict__ Az = (zone == 0) ? Xq : (zone == 1) ? Xk : Xv;

            f32x4 acc[4] = { {0,0,0,0}, {0,0,0,0}, {0,0,0,0}, {0,0,0,0} };

            const char* Ag = (const char*)(Az + (size_t)(m0 >> 6) * 16 * 4096);
            const char* Bg = (const char*)(Wt + (size_t)(n0 >> 6) * 16 * 4096);

            auto stage = [&](int bufi, int kti) {
                const char* gA = Ag + (size_t)kti * 8192 + w * 2048 + lane * 16;
                const char* gB = Bg + (size_t)kti * 8192 + w * 2048 + lane * 16;
                char* lA = (char*)&As[bufi][0] + w * 2048;
                char* lB = (char*)&Bs[bufi][0] + w * 2048;
                #pragma unroll
                for (int i = 0; i < 2; ++i) {
                    __builtin_amdgcn_global_load_lds(
                        (const __attribute__((address_space(1))) unsigned int*)(gA + i * 1024),
                        (__attribute__((address_space(3))) unsigned int*)(lA + i * 1024), 16, 0, 0);
                    __builtin_amdgcn_global_load_lds(
                        (const __attribute__((address_space(1))) unsigned int*)(gB + i * 1024),
                        (__attribute__((address_space(3))) unsigned int*)(lB + i * 1024), 16, 0, 0);
                }
            };

            stage(0, 0);
            __syncthreads();

            const int rA = 16 * w + lm;
            const int axr = rA & 7;
            for (int kt = 0; kt < 16; ++kt) {
                const int buf = kt & 1;
                if (kt < 15) stage(buf ^ 1, kt + 1);
                const char* Ab = (const char*)&As[buf][0];
                const char* Bb = (const char*)&Bs[buf][0];
                bf16x8 af0 = *reinterpret_cast<const bf16x8*>(Ab + rA * 128 + (((quad    ) ^ axr) << 4));
                bf16x8 af1 = *reinterpret_cast<const bf16x8*>(Ab + rA * 128 + (((4 | quad) ^ axr) << 4));
                #pragma unroll
                for (int nb = 0; nb < 4; ++nb) {
                    const int rB = 16 * nb + lm, bxr = rB & 7;
                    bf16x8 b0 = *reinterpret_cast<const bf16x8*>(Bb + rB * 128 + (((quad    ) ^ bxr) << 4));
                    bf16x8 b1 = *reinterpret_cast<const bf16x8*>(Bb + rB * 128 + (((4 | quad) ^ bxr) << 4));
                    acc[nb] = __builtin_amdgcn_mfma_f32_16x16x32_bf16(af0, b0, acc[nb], 0, 0, 0);
                    acc[nb] = __builtin_amdgcn_mfma_f32_16x16x32_bf16(af1, b1, acc[nb], 0, 0, 0);
                }
                __syncthreads();
            }

            const float* __restrict__ bias = (zone == 0) ? bq : (zone == 1) ? bk : bv;
            const int nbase = (zone == 0) ? n0 : (zone == 1) ? (n0 - 1024) : (n0 - 1280);
            const int head = nbase >> 6;
            #pragma unroll
            for (int nb = 0; nb < 4; ++nb) {
                const int d = 16 * nb + lm;
                const float bvv = bias[nbase + d];
                float vals[4];
                #pragma unroll
                for (int r = 0; r < 4; ++r) vals[r] = acc[nb][r] + bvv;
                if (zone != 2) {
                    const int pi = d >> 1;
                    const bool odd = (lm & 1);
                    const float sca = (zone == 0) ? QSCALE : 1.0f;
                    u16* op = (zone == 0 ? Qr : Kr) + (size_t)head * SEQ * HD;
                    #pragma unroll
                    for (int r = 0; r < 4; ++r) {
                        const int m = m0 + 16 * w + quad * 4 + r;
                        const float2 cs2 = rope[(size_t)m * 32 + pi];   // {cos, sin}
                        float x  = vals[r];
                        float xp = __shfl_xor(x, 1);
                        float o  = (odd ? (xp * cs2.y + x * cs2.x)
                                        : (x * cs2.x - xp * cs2.y)) * sca;
                        op[(size_t)m * HD + d] = f2b(o);
                    }
                } else {
                    // V transposed [kvh][d][pos], key-PERMUTED within 64-tile
                    u16* vp = Vrt + ((size_t)head * HD + d) * SEQ;
                    #pragma unroll
                    for (int r = 0; r < 4; ++r) {
                        const int m = m0 + 16 * w + quad * 4 + r;
                        const int within = m & 63;
                        const int pos = (m & ~63) + 4 * (within & 15) + (within >> 4);
                        vp[pos] = f2b(vals[r]);
                    }
                }
            }
            __syncthreads();
        }
    }
    gbar(bar, 1, NB);

    // ================================================== stage 2: attn
    {
        u16 (*Ks)[64][72] = reinterpret_cast<u16 (*)[64][72]>(SMEM);            // [2][64][72]
        u16 (*Vt)[64][72] = reinterpret_cast<u16 (*)[64][72]>(SMEM + 18432);    // [2][64][72]
        u16 (*Ps)[16][76] = reinterpret_cast<u16 (*)[16][76]>(SMEM + 36864);    // [4][16][76]

        const int bid = blockIdx.x;
        const int h  = bid & 15;
        const int qt = (bid < 256) ? (bid >> 4) : 31 - ((bid - 256) >> 4);
        const int kvh = h & 3;

        const int w = t >> 6, lane = t & 63, lm = lane & 15, quad = lane >> 4;

        {   // stage this wave's 16 Q rows into its Ps strip (wave-private)
            const int row = lane >> 2, c = (lane & 3) * 16;
            const u16* qp = Qr + ((size_t)h * SEQ + qt * 64 + w * 16 + row) * HD + c;
            *reinterpret_cast<bf16x8*>(&Ps[w][row][c])     = *reinterpret_cast<const bf16x8*>(qp);
            *reinterpret_cast<bf16x8*>(&Ps[w][row][c + 8]) = *reinterpret_cast<const bf16x8*>(qp + 8);
        }
        const bf16x8 aq0 = *reinterpret_cast<const bf16x8*>(&Ps[w][lm][quad * 8]);
        const bf16x8 aq1 = *reinterpret_cast<const bf16x8*>(&Ps[w][lm][32 + quad * 8]);

        f32x4 O[4] = { {0,0,0,0}, {0,0,0,0}, {0,0,0,0}, {0,0,0,0} };
        float lp[4] = { 0.f, 0.f, 0.f, 0.f };

        const int srow = t >> 2, sc2 = (t & 3) * 16;
        const u16* kb_ = Kr  + ((size_t)kvh * SEQ + srow) * HD + sc2;
        const u16* vb_ = Vrt + ((size_t)kvh * HD + srow) * SEQ + sc2;
        bf16x8 kR0 = *reinterpret_cast<const bf16x8*>(kb_);
        bf16x8 kR1 = *reinterpret_cast<const bf16x8*>(kb_ + 8);
        bf16x8 vR0 = *reinterpret_cast<const bf16x8*>(vb_);
        bf16x8 vR1 = *reinterpret_cast<const bf16x8*>(vb_ + 8);

        for (int kt = 0; kt <= qt; ++kt) {
            const int buf = kt & 1;
            *reinterpret_cast<bf16x8*>(&Ks[buf][srow][sc2])     = kR0;
            *reinterpret_cast<bf16x8*>(&Ks[buf][srow][sc2 + 8]) = kR1;
            *reinterpret_cast<bf16x8*>(&Vt[buf][srow][sc2])     = vR0;
            *reinterpret_cast<bf16x8*>(&Vt[buf][srow][sc2 + 8]) = vR1;
            if (kt < qt) {
                kR0 = *reinterpret_cast<const bf16x8*>(kb_ + (size_t)(kt + 1) * 64 * HD);
                kR1 = *reinterpret_cast<const bf16x8*>(kb_ + (size_t)(kt + 1) * 64 * HD + 8);
                vR0 = *reinterpret_cast<const bf16x8*>(vb_ + (size_t)(kt + 1) * 64);
                vR1 = *reinterpret_cast<const bf16x8*>(vb_ + (size_t)(kt + 1) * 64 + 8);
            }
            __syncthreads();

            f32x4 s[4];
            #pragma unroll
            for (int nb = 0; nb < 4; ++nb) {
                bf16x8 b0 = *reinterpret_cast<const bf16x8*>(&Ks[buf][16 * nb + lm][quad * 8]);
                bf16x8 b1 = *reinterpret_cast<const bf16x8*>(&Ks[buf][16 * nb + lm][32 + quad * 8]);
                f32x4 zz = { 0.f, 0.f, 0.f, 0.f };
                zz = __builtin_amdgcn_mfma_f32_16x16x32_bf16(aq0, b0, zz, 0, 0, 0);
                s[nb] = __builtin_amdgcn_mfma_f32_16x16x32_bf16(aq1, b1, zz, 0, 0, 0);
            }

            if (kt == qt) {   // causal mask (col=16nb+lm, row=16w+quad*4+r)
                #pragma unroll
                for (int nb = 0; nb < 4; ++nb)
                    #pragma unroll
                    for (int r = 0; r < 4; ++r)
                        if (16 * nb + lm > 16 * w + quad * 4 + r) s[nb][r] = -INFINITY;
            }

            #pragma unroll
            for (int r = 0; r < 4; ++r) {
                u16 pk[4];
                #pragma unroll
                for (int nb = 0; nb < 4; ++nb) {
                    float e = __builtin_amdgcn_exp2f(fminf(s[nb][r], 126.f));
                    lp[r] += e;
                    pk[nb] = f2b_fast(e);
                }
                *reinterpret_cast<uint2*>(&Ps[w][quad * 4 + r][4 * lm]) =
                    *reinterpret_cast<uint2*>(pk);
            }

            const bf16x8 ap0 = *reinterpret_cast<const bf16x8*>(&Ps[w][lm][quad * 8]);
            const bf16x8 ap1 = *reinterpret_cast<const bf16x8*>(&Ps[w][lm][32 + quad * 8]);
            #pragma unroll
            for (int db = 0; db < 4; ++db) {
                bf16x8 v0 = *reinterpret_cast<const bf16x8*>(&Vt[buf][16 * db + lm][quad * 8]);
                bf16x8 v1 = *reinterpret_cast<const bf16x8*>(&Vt[buf][16 * db + lm][32 + quad * 8]);
                O[db] = __builtin_amdgcn_mfma_f32_16x16x32_bf16(ap0, v0, O[db], 0, 0, 0);
                O[db] = __builtin_amdgcn_mfma_f32_16x16x32_bf16(ap1, v1, O[db], 0, 0, 0);
            }
        }

        #pragma unroll
        for (int r = 0; r < 4; ++r) {
            #pragma unroll
            for (int off = 1; off < 16; off <<= 1)
                lp[r] += __shfl_xor(lp[r], off);
            const float inv = 1.0f / lp[r];
            const size_t row = (size_t)(qt * 64 + 16 * w + quad * 4 + r) * DM + (size_t)h * HD;
            #pragma unroll
            for (int db = 0; db < 4; ++db)
                AO[row + 16 * db + lm] = f2b(O[db][r] * inv);
        }
    }
    gbar(bar, 2, NB);

    // ================================================== stage 3: oproj
    {
        short (*As)[64][72] = reinterpret_cast<short (*)[64][72]>(SMEM);          // [2][64][72]
        short (*Bs)[64][72] = reinterpret_cast<short (*)[64][72]>(SMEM + 18432);  // [2][64][72]
        const int w = t >> 6, lane = t & 63, lm = lane & 15, quad = lane >> 4;
        const int vb = blockIdx.x;
        const int n0 = (vb & 15) * 64, m0 = (vb >> 4) * 64;
        const int sr = t >> 2, sc = (t & 3) * 16;

        f32x4 acc[4] = { {0,0,0,0}, {0,0,0,0}, {0,0,0,0}, {0,0,0,0} };

        const u16* ap_ = AO  + (size_t)(m0 + sr) * DM + sc;
        const u16* bp_ = wot + (size_t)(n0 + sr) * DM + sc;
        bf16x8 aR0 = *reinterpret_cast<const bf16x8*>(ap_);
        bf16x8 aR1 = *reinterpret_cast<const bf16x8*>(ap_ + 8);
        bf16x8 bR0 = *reinterpret_cast<const bf16x8*>(bp_);
        bf16x8 bR1 = *reinterpret_cast<const bf16x8*>(bp_ + 8);

        for (int k0 = 0; k0 < DM; k0 += 64) {
            const int buf = (k0 >> 6) & 1;
            *reinterpret_cast<bf16x8*>(&As[buf][sr][sc])     = aR0;
            *reinterpret_cast<bf16x8*>(&As[buf][sr][sc + 8]) = aR1;
            *reinterpret_cast<bf16x8*>(&Bs[buf][sr][sc])     = bR0;
            *reinterpret_cast<bf16x8*>(&Bs[buf][sr][sc + 8]) = bR1;
            if (k0 + 64 < DM) {
                aR0 = *reinterpret_cast<const bf16x8*>(ap_ + k0 + 64);
                aR1 = *reinterpret_cast<const bf16x8*>(ap_ + k0 + 72);
                bR0 = *reinterpret_cast<const bf16x8*>(bp_ + k0 + 64);
                bR1 = *reinterpret_cast<const bf16x8*>(bp_ + k0 + 72);
            }
            __syncthreads();
            bf16x8 af0 = *reinterpret_cast<const bf16x8*>(&As[buf][16 * w + lm][quad * 8]);
            bf16x8 af1 = *reinterpret_cast<const bf16x8*>(&As[buf][16 * w + lm][32 + quad * 8]);
            #pragma unroll
            for (int nb = 0; nb < 4; ++nb) {
                bf16x8 b0 = *reinterpret_cast<const bf16x8*>(&Bs[buf][16 * nb + lm][quad * 8]);
                bf16x8 b1 = *reinterpret_cast<const bf16x8*>(&Bs[buf][16 * nb + lm][32 + quad * 8]);
                acc[nb] = __builtin_amdgcn_mfma_f32_16x16x32_bf16(af0, b0, acc[nb], 0, 0, 0);
                acc[nb] = __builtin_amdgcn_mfma_f32_16x16x32_bf16(af1, b1, acc[nb], 0, 0, 0);
            }
            __syncthreads();
        }

        #pragma unroll
        for (int nb = 0; nb < 4; ++nb) {
            const int dl = 16 * nb + lm;
            const float bv2 = bo[n0 + dl];
            #pragma unroll
            for (int r = 0; r < 4; ++r) {
                const int m = m0 + 16 * w + quad * 4 + r;
                out[(size_t)m * DM + n0 + dl] = acc[nb][r] + bv2;
            }
        }
    }
}

// ---------------------------------------------------------------- launcher
extern "C" void kernel_launch(void* const* d_in, const int* in_sizes, int n_in,
                              void* d_out, int out_size, void* d_ws, size_t ws_size,
                              hipStream_t stream)
{
    const float* q  = (const float*)d_in[0];
    const float* k  = (const float*)d_in[1];
    const float* v  = (const float*)d_in[2];
    // d_in[3] = mask (int32) — causal tril, handled analytically
    const float* Wq = (const float*)d_in[4];
    const float* bq = (const float*)d_in[5];
    const float* Wk = (const float*)d_in[6];
    const float* bk = (const float*)d_in[7];
    const float* Wv = (const float*)d_in[8];
    const float* bv = (const float*)d_in[9];
    const float* Wo = (const float*)d_in[10];
    const float* bo = (const float*)d_in[11];
    float* out = (float*)d_out;

    u16* Xq  = (u16*)d_ws;                          // [32][16] tiles of 64x64 (swz)
    u16* Xk  = Xq  + (size_t)SEQ * DM;
    u16* Xv  = Xk  + (size_t)SEQ * DM;
    u16* Wt  = Xv  + (size_t)SEQ * DM;              // [24][16] tiles of 64x64 (swz)
    u16* wot = Wt  + (size_t)1536 * 1024;           // [1024][1024] row-major
    u16* Qr  = wot + (size_t)1024 * 1024;           // [16][2048][64]
    u16* Kr  = Qr  + (size_t)16 * SEQ * HD;         // [4][2048][64]
    u16* Vrt = Kr  + (size_t)4 * SEQ * HD;          // [4][64][2048] key-permuted
    u16* AO  = Vrt + (size_t)4 * SEQ * HD;          // [2048][1024]
    float2* rope = (float2*)(AO + (size_t)SEQ * DM); // [2048][32] {cos,sin} f32
    unsigned int* bar = (unsigned int*)((char*)d_ws + ((size_t)32 << 20)); // @+32MB

    hipMemsetAsync(bar, 0, 64, stream);             // zero barrier state (capturable)

    void* args[] = {
        (void*)&q, (void*)&k, (void*)&v,
        (void*)&Wq, (void*)&Wk, (void*)&Wv, (void*)&Wo,
        (void*)&bq, (void*)&bk, (void*)&bv, (void*)&bo,
        (void*)&out,
        (void*)&Xq, (void*)&Xk, (void*)&Xv, (void*)&Wt, (void*)&wot,
        (void*)&Qr, (void*)&Kr, (void*)&Vrt, (void*)&AO, (void*)&rope,
        (void*)&bar
    };
    hipLaunchKernelGGL(gqa_fused, dim3(512), dim3(256), 0, stream,
                       q, k, v, Wq, Wk, Wv, Wo, bq, bk, bv, bo, out,
                       Xq, Xk, Xv, Wt, wot, Qr, Kr, Vrt, AO, rope, bar);
    (void)args;
}

// Round 9
// 177.339 us; speedup vs baseline: 2.0476x; 2.0476x over previous
//
#include <hip/hip_runtime.h>
#include <hip/hip_bf16.h>
#include <math.h>

// GQA attention forward, MI355X. Round 17: r13 base + T4 counted-vmcnt GEMMs.
//  - proj/oproj: 2-barrier counted-vmcnt schedule (loads never drained to 0 in
//    steady state): vmcnt(4) -> s_barrier -> compute -> s_barrier -> gll(kt+2).
//  - wot + AO now tiled 64x64 + XOR-swizzled (like Wt/Xq): prep Wo branch and
//    attn epilogue write the tiled layout; oproj = proj-style gll GEMM.
//  - attn: + s_setprio(1) around MFMA clusters (independent blocks per CU).
//  - fused/SW-barrier abandoned (r16: contended spin cost ~160us).
// ws (u16): Xq 2M | Xk 2M | Xv 2M | Wt 1.5M | wot 1M | Qr 2M | Kr 512K | Vrt 512K | AO 2M | rope 512KB(f32)

#define SEQ 2048
#define DM 1024
#define HD 64

using u16 = unsigned short;
typedef __attribute__((ext_vector_type(8))) short bf16x8;
typedef __attribute__((ext_vector_type(4))) float f32x4;

#define QSCALE 0.18033688011112042f   // 1/sqrt(64) * log2(e)

__device__ __forceinline__ u16 f2b(float f) {              // RNE
    union { float f; unsigned int i; } v; v.f = f;
    unsigned int u = v.i;
    return (u16)((u + 0x7fffu + ((u >> 16) & 1u)) >> 16);
}
__device__ __forceinline__ u16 f2b_fast(float f) {         // biased round
    union { float f; unsigned int i; } v; v.f = f;
    return (u16)((v.i + 0x8000u) >> 16);
}

#define VMCNT4 do { asm volatile("s_waitcnt vmcnt(4)" ::: "memory"); \
                    __builtin_amdgcn_sched_barrier(0); } while (0)
#define VMCNT0 do { asm volatile("s_waitcnt vmcnt(0)" ::: "memory"); \
                    __builtin_amdgcn_sched_barrier(0); } while (0)

// ---------------------------------------------------------------- prep
// [0,640): weight 64x64 transposes fp32 -> bf16, ALL tiled+swizzled now
//          (b<384 -> Wt, else -> wot). [640,1408): q/k/v -> bf16 swz tiles.
// [1408,1416): RoPE table rope[m][pi] = {cos,sin}.
__global__ __launch_bounds__(256) void prep_kernel(
    const float* __restrict__ qin, const float* __restrict__ kin, const float* __restrict__ vin,
    const float* __restrict__ Wq, const float* __restrict__ Wk,
    const float* __restrict__ Wv, const float* __restrict__ Wo,
    u16* __restrict__ Xq, u16* __restrict__ Xk, u16* __restrict__ Xv,
    u16* __restrict__ Wt, u16* __restrict__ wot, float2* __restrict__ rope)
{
    const int b = blockIdx.x;
    const int t = threadIdx.x;

    if (b < 640) {
        __shared__ short T[64][72];
        const float* W; u16* dst; int N, t0, rowoff;
        if (b < 256)      { W = Wq; dst = Wt;  N = 1024; t0 = b;       rowoff = 0; }
        else if (b < 320) { W = Wk; dst = Wt;  N = 256;  t0 = b - 256; rowoff = 1024; }
        else if (b < 384) { W = Wv; dst = Wt;  N = 256;  t0 = b - 320; rowoff = 1280; }
        else              { W = Wo; dst = wot; N = 1024; t0 = b - 384; rowoff = 0; }
        const int ntn = N >> 6;
        const int k0 = (t0 / ntn) * 64, n0 = (t0 % ntn) * 64;
        const int r = t >> 4, c4 = (t & 15) * 4;
        #pragma unroll
        for (int rr = 0; rr < 4; ++rr) {
            const int k = r + rr * 16;
            float4 w4 = *reinterpret_cast<const float4*>(W + (size_t)(k0 + k) * N + n0 + c4);
            T[c4 + 0][k] = (short)f2b(w4.x);
            T[c4 + 1][k] = (short)f2b(w4.y);
            T[c4 + 2][k] = (short)f2b(w4.z);
            T[c4 + 3][k] = (short)f2b(w4.w);
        }
        __syncthreads();
        const int n = t >> 2, ck = (t & 3) * 16;
        // tiled + swizzled store (both Wt and wot)
        const int nt = (rowoff + n0) >> 6, kt = k0 >> 6;
        char* dp = (char*)(dst + (size_t)(nt * 16 + kt) * 4096) + n * 128;
        const int g0 = (t & 3) * 2, rx = n & 7;
        *reinterpret_cast<bf16x8*>(dp + (((g0    ) ^ rx) << 4)) =
            *reinterpret_cast<const bf16x8*>(&T[n][ck]);
        *reinterpret_cast<bf16x8*>(dp + (((g0 + 1) ^ rx) << 4)) =
            *reinterpret_cast<const bf16x8*>(&T[n][ck + 8]);
    } else if (b < 1408) {
        const int idx = b - 640;
        const int which = idx >> 8;
        const int ib = idx & 255;
        const float* src = (which == 0) ? qin : (which == 1) ? kin : vin;
        u16* dst = (which == 0) ? Xq : (which == 1) ? Xk : Xv;
        const int m  = ib * 8 + (t >> 5);          // global row
        const int mt = m >> 6, r = m & 63, rx = r & 7;
        const int col0 = (t & 31) * 32;
        const float* sp = src + (size_t)m * 1024 + col0;
        #pragma unroll
        for (int c = 0; c < 4; ++c) {
            float4 x0 = *reinterpret_cast<const float4*>(sp + c * 8);
            float4 x1 = *reinterpret_cast<const float4*>(sp + c * 8 + 4);
            bf16x8 o;
            o[0] = (short)f2b(x0.x); o[1] = (short)f2b(x0.y);
            o[2] = (short)f2b(x0.z); o[3] = (short)f2b(x0.w);
            o[4] = (short)f2b(x1.x); o[5] = (short)f2b(x1.y);
            o[6] = (short)f2b(x1.z); o[7] = (short)f2b(x1.w);
            const int col = col0 + c * 8;
            const int kt = col >> 6, g = (col & 63) >> 3;
            char* dp = (char*)(dst + (size_t)(mt * 16 + kt) * 4096)
                     + r * 128 + ((g ^ rx) << 4);
            *reinterpret_cast<bf16x8*>(dp) = o;
        }
    } else {
        const int m = (b - 1408) * 256 + t;
        float2* rp = rope + (size_t)m * 32;
        for (int pi = 0; pi < 32; ++pi) {
            const float theta = exp2f(-0.8304820237f * (float)pi);  // 10000^(-pi/16)
            float sn, cs;
            sincosf((float)m * theta, &sn, &cs);
            rp[pi] = make_float2(cs, sn);
        }
    }
}

// ---------------------------------------------------------------- shared GEMM core
// gll staging from swizzled 64x64 tiles, counted-vmcnt 2-barrier schedule.
// Ring-2 LDS (As/Bs dbuf). Steady state: 2 tiles (8 loads/wave) in flight.
template <typename EPI>
__device__ __forceinline__ void gemm64_core(
    const char* Ag, const char* Bg, u16 (*As)[4096], u16 (*Bs)[4096],
    int t, EPI&& epilogue)
{
    const int w = t >> 6, lane = t & 63, lm = lane & 15, quad = lane >> 4;

    f32x4 acc[4] = { {0,0,0,0}, {0,0,0,0}, {0,0,0,0}, {0,0,0,0} };

    auto stage = [&](int bufi, int kti) {
        const char* gA = Ag + (size_t)kti * 8192 + w * 2048 + lane * 16;
        const char* gB = Bg + (size_t)kti * 8192 + w * 2048 + lane * 16;
        char* lA = (char*)&As[bufi][0] + w * 2048;
        char* lB = (char*)&Bs[bufi][0] + w * 2048;
        #pragma unroll
        for (int i = 0; i < 2; ++i) {
            __builtin_amdgcn_global_load_lds(
                (const __attribute__((address_space(1))) unsigned int*)(gA + i * 1024),
                (__attribute__((address_space(3))) unsigned int*)(lA + i * 1024), 16, 0, 0);
            __builtin_amdgcn_global_load_lds(
                (const __attribute__((address_space(1))) unsigned int*)(gB + i * 1024),
                (__attribute__((address_space(3))) unsigned int*)(lB + i * 1024), 16, 0, 0);
        }
    };

    stage(0, 0);
    stage(1, 1);

    const int rA = 16 * w + lm;
    const int axr = rA & 7;
    for (int kt = 0; kt < 16; ++kt) {
        const int buf = kt & 1;
        if (kt < 15) { VMCNT4; } else { VMCNT0; }   // drain tile kt, keep kt+1 flying
        __builtin_amdgcn_s_barrier();
        __builtin_amdgcn_sched_barrier(0);
        const char* Ab = (const char*)&As[buf][0];
        const char* Bb = (const char*)&Bs[buf][0];
        bf16x8 af0 = *reinterpret_cast<const bf16x8*>(Ab + rA * 128 + (((quad    ) ^ axr) << 4));
        bf16x8 af1 = *reinterpret_cast<const bf16x8*>(Ab + rA * 128 + (((4 | quad) ^ axr) << 4));
        #pragma unroll
        for (int nb = 0; nb < 4; ++nb) {
            const int rB = 16 * nb + lm, bxr = rB & 7;
            bf16x8 b0 = *reinterpret_cast<const bf16x8*>(Bb + rB * 128 + (((quad    ) ^ bxr) << 4));
            bf16x8 b1 = *reinterpret_cast<const bf16x8*>(Bb + rB * 128 + (((4 | quad) ^ bxr) << 4));
            acc[nb] = __builtin_amdgcn_mfma_f32_16x16x32_bf16(af0, b0, acc[nb], 0, 0, 0);
            acc[nb] = __builtin_amdgcn_mfma_f32_16x16x32_bf16(af1, b1, acc[nb], 0, 0, 0);
        }
        __builtin_amdgcn_sched_barrier(0);
        __builtin_amdgcn_s_barrier();               // readers of S[buf] done
        if (kt < 14) stage(buf, kt + 2);            // refill just-freed slot
    }
    epilogue(acc, w, lm, quad);
}

// ---------------------------------------------------------------- projections
__global__ __launch_bounds__(256) void proj_mfma(
    const u16* __restrict__ Xq, const u16* __restrict__ Xk, const u16* __restrict__ Xv,
    const u16* __restrict__ Wt,
    const float* __restrict__ bq, const float* __restrict__ bk, const float* __restrict__ bv,
    const float2* __restrict__ rope,
    u16* __restrict__ Qr, u16* __restrict__ Kr, u16* __restrict__ Vrt)
{
    const int n0 = blockIdx.x * 64, m0 = blockIdx.y * 64;
    const int zone = (n0 < 1024) ? 0 : (n0 < 1280) ? 1 : 2;
    const u16* __restrict__ Az = (zone == 0) ? Xq : (zone == 1) ? Xk : Xv;

    __shared__ __align__(16) u16 As[2][4096];
    __shared__ __align__(16) u16 Bs[2][4096];

    const char* Ag = (const char*)(Az + (size_t)(m0 >> 6) * 16 * 4096);
    const char* Bg = (const char*)(Wt + (size_t)(n0 >> 6) * 16 * 4096);

    gemm64_core(Ag, Bg, As, Bs, threadIdx.x,
        [&](f32x4 (&acc)[4], int w, int lm, int quad) {
            const float* __restrict__ bias = (zone == 0) ? bq : (zone == 1) ? bk : bv;
            const int nbase = (zone == 0) ? n0 : (zone == 1) ? (n0 - 1024) : (n0 - 1280);
            const int head = nbase >> 6;
            #pragma unroll
            for (int nb = 0; nb < 4; ++nb) {
                const int d = 16 * nb + lm;
                const float bvv = bias[nbase + d];
                float vals[4];
                #pragma unroll
                for (int r = 0; r < 4; ++r) vals[r] = acc[nb][r] + bvv;
                if (zone != 2) {
                    const int pi = d >> 1;
                    const bool odd = (lm & 1);
                    const float sca = (zone == 0) ? QSCALE : 1.0f;
                    u16* op = (zone == 0 ? Qr : Kr) + (size_t)head * SEQ * HD;
                    #pragma unroll
                    for (int r = 0; r < 4; ++r) {
                        const int m = m0 + 16 * w + quad * 4 + r;
                        const float2 cs2 = rope[(size_t)m * 32 + pi];
                        float x  = vals[r];
                        float xp = __shfl_xor(x, 1);
                        float o  = (odd ? (xp * cs2.y + x * cs2.x)
                                        : (x * cs2.x - xp * cs2.y)) * sca;
                        op[(size_t)m * HD + d] = f2b(o);
                    }
                } else {
                    // V transposed [kvh][d][pos], key-PERMUTED within 64-tile
                    u16* vp = Vrt + ((size_t)head * HD + d) * SEQ;
                    #pragma unroll
                    for (int r = 0; r < 4; ++r) {
                        const int m = m0 + 16 * w + quad * 4 + r;
                        const int within = m & 63;
                        const int pos = (m & ~63) + 4 * (within & 15) + (within >> 4);
                        vp[pos] = f2b(vals[r]);
                    }
                }
            }
        });
}

// ---------------------------------------------------------------- attention
// 512 blocks x 256 threads; identical to r13 except: AO written tiled+swizzled
// (for oproj gll) and s_setprio around MFMA clusters.
__global__ __launch_bounds__(256) void attn_mfma(
    const u16* __restrict__ Qr, const u16* __restrict__ Kr, const u16* __restrict__ Vrt,
    u16* __restrict__ AO)
{
    const int bid = blockIdx.x;
    const int h  = bid & 15;
    const int qt = (bid < 256) ? (bid >> 4) : 31 - ((bid - 256) >> 4);
    const int kvh = h & 3;

    __shared__ u16 Ks[2][64][72];     // [key][d]
    __shared__ u16 Vt[2][64][72];     // [d][c]  (c = permuted key)
    __shared__ u16 Ps[4][16][76];     // per-wave strip; also Q staging

    const int t = threadIdx.x;
    const int w = t >> 6, lane = t & 63, lm = lane & 15, quad = lane >> 4;

    {
        const int row = lane >> 2, c = (lane & 3) * 16;
        const u16* qp = Qr + ((size_t)h * SEQ + qt * 64 + w * 16 + row) * HD + c;
        *reinterpret_cast<bf16x8*>(&Ps[w][row][c])     = *reinterpret_cast<const bf16x8*>(qp);
        *reinterpret_cast<bf16x8*>(&Ps[w][row][c + 8]) = *reinterpret_cast<const bf16x8*>(qp + 8);
    }
    const bf16x8 aq0 = *reinterpret_cast<const bf16x8*>(&Ps[w][lm][quad * 8]);
    const bf16x8 aq1 = *reinterpret_cast<const bf16x8*>(&Ps[w][lm][32 + quad * 8]);

    f32x4 O[4] = { {0,0,0,0}, {0,0,0,0}, {0,0,0,0}, {0,0,0,0} };
    float lp[4] = { 0.f, 0.f, 0.f, 0.f };

    const int srow = t >> 2, sc2 = (t & 3) * 16;
    const u16* kb_ = Kr  + ((size_t)kvh * SEQ + srow) * HD + sc2;
    const u16* vb_ = Vrt + ((size_t)kvh * HD + srow) * SEQ + sc2;
    bf16x8 kR0 = *reinterpret_cast<const bf16x8*>(kb_);
    bf16x8 kR1 = *reinterpret_cast<const bf16x8*>(kb_ + 8);
    bf16x8 vR0 = *reinterpret_cast<const bf16x8*>(vb_);
    bf16x8 vR1 = *reinterpret_cast<const bf16x8*>(vb_ + 8);

    for (int kt = 0; kt <= qt; ++kt) {
        const int buf = kt & 1;
        *reinterpret_cast<bf16x8*>(&Ks[buf][srow][sc2])     = kR0;
        *reinterpret_cast<bf16x8*>(&Ks[buf][srow][sc2 + 8]) = kR1;
        *reinterpret_cast<bf16x8*>(&Vt[buf][srow][sc2])     = vR0;
        *reinterpret_cast<bf16x8*>(&Vt[buf][srow][sc2 + 8]) = vR1;
        if (kt < qt) {
            kR0 = *reinterpret_cast<const bf16x8*>(kb_ + (size_t)(kt + 1) * 64 * HD);
            kR1 = *reinterpret_cast<const bf16x8*>(kb_ + (size_t)(kt + 1) * 64 * HD + 8);
            vR0 = *reinterpret_cast<const bf16x8*>(vb_ + (size_t)(kt + 1) * 64);
            vR1 = *reinterpret_cast<const bf16x8*>(vb_ + (size_t)(kt + 1) * 64 + 8);
        }
        __syncthreads();

        f32x4 s[4];
        __builtin_amdgcn_s_setprio(1);
        #pragma unroll
        for (int nb = 0; nb < 4; ++nb) {
            bf16x8 b0 = *reinterpret_cast<const bf16x8*>(&Ks[buf][16 * nb + lm][quad * 8]);
            bf16x8 b1 = *reinterpret_cast<const bf16x8*>(&Ks[buf][16 * nb + lm][32 + quad * 8]);
            f32x4 zz = { 0.f, 0.f, 0.f, 0.f };
            zz = __builtin_amdgcn_mfma_f32_16x16x32_bf16(aq0, b0, zz, 0, 0, 0);
            s[nb] = __builtin_amdgcn_mfma_f32_16x16x32_bf16(aq1, b1, zz, 0, 0, 0);
        }
        __builtin_amdgcn_s_setprio(0);

        if (kt == qt) {
            #pragma unroll
            for (int nb = 0; nb < 4; ++nb)
                #pragma unroll
                for (int r = 0; r < 4; ++r)
                    if (16 * nb + lm > 16 * w + quad * 4 + r) s[nb][r] = -INFINITY;
        }

        #pragma unroll
        for (int r = 0; r < 4; ++r) {
            u16 pk[4];
            #pragma unroll
            for (int nb = 0; nb < 4; ++nb) {
                float e = __builtin_amdgcn_exp2f(fminf(s[nb][r], 126.f));
                lp[r] += e;
                pk[nb] = f2b_fast(e);
            }
            *reinterpret_cast<uint2*>(&Ps[w][quad * 4 + r][4 * lm]) =
                *reinterpret_cast<uint2*>(pk);
        }

        const bf16x8 ap0 = *reinterpret_cast<const bf16x8*>(&Ps[w][lm][quad * 8]);
        const bf16x8 ap1 = *reinterpret_cast<const bf16x8*>(&Ps[w][lm][32 + quad * 8]);
        __builtin_amdgcn_s_setprio(1);
        #pragma unroll
        for (int db = 0; db < 4; ++db) {
            bf16x8 v0 = *reinterpret_cast<const bf16x8*>(&Vt[buf][16 * db + lm][quad * 8]);
            bf16x8 v1 = *reinterpret_cast<const bf16x8*>(&Vt[buf][16 * db + lm][32 + quad * 8]);
            O[db] = __builtin_amdgcn_mfma_f32_16x16x32_bf16(ap0, v0, O[db], 0, 0, 0);
            O[db] = __builtin_amdgcn_mfma_f32_16x16x32_bf16(ap1, v1, O[db], 0, 0, 0);
        }
        __builtin_amdgcn_s_setprio(0);
    }

    // AO write, TILED+SWIZZLED: tile (qt*16 + h), elem (r_in, c=16db+lm):
    // off = tile*4096 + r_in*64 + ((g ^ (r_in&7))<<3) + (c&7), g = 2db + (lm>>3)
    #pragma unroll
    for (int r = 0; r < 4; ++r) {
        #pragma unroll
        for (int off = 1; off < 16; off <<= 1)
            lp[r] += __shfl_xor(lp[r], off);
        const float inv = 1.0f / lp[r];
        const int r_in = 16 * w + quad * 4 + r;
        const int rx = r_in & 7;
        u16* tp = AO + (size_t)(qt * 16 + h) * 4096 + r_in * 64;
        #pragma unroll
        for (int db = 0; db < 4; ++db) {
            const int c = 16 * db + lm;
            const int g = (c >> 3);
            tp[((g ^ rx) << 3) + (c & 7)] = f2b(O[db][r] * inv);
        }
    }
}

// ---------------------------------------------------------------- output proj
// grid (16, 32): AO(tiled swz) @ wot(tiled swz) + bo -> fp32 out.
__global__ __launch_bounds__(256) void oproj_mfma(
    const u16* __restrict__ AO, const u16* __restrict__ wot,
    const float* __restrict__ bo, float* __restrict__ out)
{
    __shared__ __align__(16) u16 As[2][4096];
    __shared__ __align__(16) u16 Bs[2][4096];
    const int m0 = blockIdx.y * 64, n0 = blockIdx.x * 64;

    const char* Ag = (const char*)(AO  + (size_t)(m0 >> 6) * 16 * 4096);
    const char* Bg = (const char*)(wot + (size_t)(n0 >> 6) * 16 * 4096);

    gemm64_core(Ag, Bg, As, Bs, threadIdx.x,
        [&](f32x4 (&acc)[4], int w, int lm, int quad) {
            #pragma unroll
            for (int nb = 0; nb < 4; ++nb) {
                const int dl = 16 * nb + lm;
                const float bv = bo[n0 + dl];
                #pragma unroll
                for (int r = 0; r < 4; ++r) {
                    const int m = m0 + 16 * w + quad * 4 + r;
                    out[(size_t)m * DM + n0 + dl] = acc[nb][r] + bv;
                }
            }
        });
}

// ---------------------------------------------------------------- launcher
extern "C" void kernel_launch(void* const* d_in, const int* in_sizes, int n_in,
                              void* d_out, int out_size, void* d_ws, size_t ws_size,
                              hipStream_t stream)
{
    const float* q  = (const float*)d_in[0];
    const float* k  = (const float*)d_in[1];
    const float* v  = (const float*)d_in[2];
    // d_in[3] = mask (int32) — causal tril, handled analytically
    const float* Wq = (const float*)d_in[4];
    const float* bq = (const float*)d_in[5];
    const float* Wk = (const float*)d_in[6];
    const float* bk = (const float*)d_in[7];
    const float* Wv = (const float*)d_in[8];
    const float* bv = (const float*)d_in[9];
    const float* Wo = (const float*)d_in[10];
    const float* bo = (const float*)d_in[11];
    float* out = (float*)d_out;

    u16* Xq  = (u16*)d_ws;                          // [32][16] tiles of 64x64 (swz)
    u16* Xk  = Xq  + (size_t)SEQ * DM;
    u16* Xv  = Xk  + (size_t)SEQ * DM;
    u16* Wt  = Xv  + (size_t)SEQ * DM;              // [24][16] tiles (swz)
    u16* wot = Wt  + (size_t)1536 * 1024;           // [16][16] tiles (swz)
    u16* Qr  = wot + (size_t)1024 * 1024;           // [16][2048][64]
    u16* Kr  = Qr  + (size_t)16 * SEQ * HD;         // [4][2048][64]
    u16* Vrt = Kr  + (size_t)4 * SEQ * HD;          // [4][64][2048] key-permuted
    u16* AO  = Vrt + (size_t)4 * SEQ * HD;          // [32][16] tiles (swz)
    float2* rope = (float2*)(AO + (size_t)SEQ * DM); // [2048][32] {cos,sin} f32

    hipLaunchKernelGGL(prep_kernel, dim3(1416), dim3(256), 0, stream,
                       q, k, v, Wq, Wk, Wv, Wo, Xq, Xk, Xv, Wt, wot, rope);
    hipLaunchKernelGGL(proj_mfma, dim3(24, 32), dim3(256), 0, stream,
                       Xq, Xk, Xv, Wt, bq, bk, bv, rope, Qr, Kr, Vrt);
    hipLaunchKernelGGL(attn_mfma, dim3(512), dim3(256), 0, stream,
                       Qr, Kr, Vrt, AO);
    hipLaunchKernelGGL(oproj_mfma, dim3(16, 32), dim3(256), 0, stream,
                       AO, wot, bo, out);
}